// Round 14
// baseline (98.683 us; speedup 1.0000x reference)
//
#include <hip/hip_runtime.h>
#include <hip/hip_fp16.h>

// GeneSymbolCNN: embed(67x32, pad0) -> conv1d k=2/3/4 (32ch) + ReLU + max_t
//                -> concat(96) -> 96x96 linear + ReLU.
// R14: persistent grid + pair-table loads with cap-respecting batches.
//  * PERSISTENT: grid 512 = exactly 2 blocks/CU resident; each block runs
//    2 row-chunks (bid, bid+512). No generations -> no lone-block tail
//    (R8's last ~1/3: lone block at 8 waves ran ~10-13us). LDS staged ONCE.
//  * conv2 = P2[x_p,x_{p+1}] (15 global loads, L2-resident 287KB table);
//    conv4 = P4a[..]+P4b[..] (26 loads, 2 tables);
//    conv3 = 3-tap LDS lookup (42 reads, tables T2,T3,T4 parity-replicated,
//    25.7KB). Per-thread LDS 124 -> 42.
//  * R7/R9/R10 squeeze post-mortem: those asked for >VGPR-cap liveness ->
//    allocator serialized loads. Here batches A(15)/C(12)/D(14) are each
//    consumed before the next issues; peak live ~115 < 128 cap (512,4).
//    sched_barrier(0) after each issue stops load sinking.
//  * Projection: conv v8h output IS the mfma A-fragment (since R6).
// Fallback (ws too small): R8 all-LDS kernel.

#define VOCABSZ 67
#define EMBSZ   32
#define NCH     32
#define NFEAT   96
#define SEQL    16
#define BATCH   131072
#define NTAB    9
#define NFP     (NFEAT / 2)
#define TABU    9648                   // 603 entries * 16 u32 (f16 tap tables)
#define PWOFF   9648                   // packed pw follows
#define NPW     4608
#define PAIRW   (TABU + NPW)           // 14256: pair tables start (u32)
#define NPAIR   (VOCABSZ * VOCABSZ)    // 4489
#define PRW     (NPAIR * 16)           // 71824 u32 per pair table
#define PRB     (NPAIR * 64)           // 287296 B per pair table
#define WSNEED  ((PAIRW + 3 * PRW) * 4)   // 918,912 B
#define T3LDS   (201 * 128)            // 25728 B: T2,T3,T4 parity-replicated
// fallback geometry (R8)
#define ESTR    80
#define LTS     (VOCABSZ * ESTR)
#define LDSB8   (NTAB * LTS)           // 48240

typedef _Float16 v2h __attribute__((ext_vector_type(2)));
typedef _Float16 v8h __attribute__((ext_vector_type(8)));
typedef float    v4f __attribute__((ext_vector_type(4)));

#define SB() __builtin_amdgcn_sched_barrier(0)

__device__ __forceinline__ unsigned packh2(float a, float b) {
    v2h p; p[0] = (_Float16)a; p[1] = (_Float16)b;
    return __builtin_bit_cast(unsigned, p);
}
__device__ __forceinline__ v8h vmax8(v8h a, v8h b) {
    return __builtin_elementwise_max(a, b);
}

// ------------- kernel 1: f16 tap tables (j=0..8, bias in h=0) + packed pw --
__global__ __launch_bounds__(256) void build_tables(
    const float* __restrict__ embed,
    const float* __restrict__ w2, const float* __restrict__ b2,
    const float* __restrict__ w3, const float* __restrict__ b3,
    const float* __restrict__ w4, const float* __restrict__ b4,
    const float* __restrict__ pw,
    unsigned* __restrict__ ws)
{
    int idx = blockIdx.x * 256 + threadIdx.x;
    if (idx < TABU) {
        int cp = idx & 15;
        int t  = idx >> 4;
        int j  = t / VOCABSZ;
        int v  = t - j * VOCABSZ;
        const float* w; const float* bias; int k, h;
        if (j < 2)      { w = w2; k = 2; h = j;     bias = (h == 0) ? b2 : nullptr; }
        else if (j < 5) { w = w3; k = 3; h = j - 2; bias = (h == 0) ? b3 : nullptr; }
        else            { w = w4; k = 4; h = j - 5; bias = (h == 0) ? b4 : nullptr; }
        int c0 = 2 * cp;
        float a0 = bias ? bias[c0]     : 0.0f;
        float a1 = bias ? bias[c0 + 1] : 0.0f;
        if (v != 0) {                  // padding_idx=0: row 0 zeros
            #pragma unroll
            for (int e = 0; e < EMBSZ; ++e) {
                float ev = embed[v * EMBSZ + e];
                a0 += ev * w[((c0    ) * EMBSZ + e) * k + h];
                a1 += ev * w[((c0 + 1) * EMBSZ + e) * k + h];
            }
        }
        ws[t * 16 + cp] = packh2(a0, a1);
    } else if (idx < PAIRW) {          // packed pw: pwh[o][fp]
        int i  = idx - PWOFF;
        int o  = i / NFP;
        int fp = i - o * NFP;
        ws[idx] = packh2(pw[o * NFEAT + 2 * fp], pw[o * NFEAT + 2 * fp + 1]);
    }
}

// ------------- kernel 1b: pair tables P[a,b]=T_j0[a]+T_{j0+1}[b] ----------
// g=0: T0+T1 (conv2). g=1: T5+T6 (P4a). g=2: T7+T8 (P4b). conv3 stays LDS.
__global__ __launch_bounds__(256) void build_pairs3(unsigned* __restrict__ ws)
{
    int idx = blockIdx.x * 256 + threadIdx.x;
    if (idx >= 3 * PRW) return;
    int g = idx / PRW;
    int r = idx - g * PRW;
    int e = r >> 4;
    int w = r & 15;
    int a = e / VOCABSZ;
    int b = e - a * VOCABSZ;
    int j0 = (g == 0) ? 0 : (g == 1) ? 5 : 7;
    unsigned ua = ws[((j0    ) * VOCABSZ + a) * 16 + w];
    unsigned ub = ws[((j0 + 1) * VOCABSZ + b) * 16 + w];
    v2h s = __builtin_bit_cast(v2h, ua) + __builtin_bit_cast(v2h, ub);
    ws[PAIRW + idx] = __builtin_bit_cast(unsigned, s);
}

// ------------- kernel 2 (R14): persistent pair-conv + MFMA projection -----
__global__ __launch_bounds__(512, 4) void fused_cnn(
    const int*      __restrict__ x,
    const unsigned* __restrict__ ws,
    const float*    __restrict__ pb,
    float*          __restrict__ out)
{
    __shared__ __align__(16) char lds[T3LDS];
    const int tid = threadIdx.x;
    {   // stage T2,T3,T4 (201 entries x 64B) parity-replicated, ONCE
        const float4* s4 = reinterpret_cast<const float4*>(ws);
        float4* d4 = reinterpret_cast<float4*>(lds);
        for (int i = tid; i < 804; i += 512) {
            int t = i >> 2, cc = i & 3;          // t = local entry 0..200
            float4 v = s4[536 + 4 * t + cc];     // src entry 134+t (j=2..4)
            d4[t * 8 + cc]     = v;              // parity 0
            d4[t * 8 + 4 + cc] = v;              // parity 1 (+64B)
        }
    }
    __syncthreads();

    const int lane = tid & 63;
    const int wv   = tid >> 6;
    const int ml   = lane & 15;                  // batch row in wave tile
    const int c    = lane >> 4;                  // MFMA k-group / chunk
    const int co   = c << 4;
    const int parc = (((lane >> 3) & 1) << 6) + co;  // LDS parity+chunk
    const char* g2  = reinterpret_cast<const char*>(ws + PAIRW);
    const char* g4a = g2 + PRB;
    const char* g4b = g2 + 2 * PRB;
    const unsigned* __restrict__ pwp = ws + PWOFF + ml * NFP + c * 4;

    #pragma unroll 1
    for (int k = 0; k < 2; ++k) {                // persistent: 2 chunks/block
        const int rowb = (blockIdx.x + k * 512) * 128 + wv * 16;
        const int row  = rowb + ml;

        const int4* xp = reinterpret_cast<const int4*>(x + row * SEQL);
        int4 q0 = xp[0], q1 = xp[1], q2 = xp[2], q3 = xp[3];
        int tq[16];
        tq[ 0] = q0.x; tq[ 1] = q0.y; tq[ 2] = q0.z; tq[ 3] = q0.w;
        tq[ 4] = q1.x; tq[ 5] = q1.y; tq[ 6] = q1.z; tq[ 7] = q1.w;
        tq[ 8] = q2.x; tq[ 9] = q2.y; tq[10] = q2.z; tq[11] = q2.w;
        tq[12] = q3.x; tq[13] = q3.y; tq[14] = q3.z; tq[15] = q3.w;

        int pr[15];                              // pair-entry byte offsets
        #pragma unroll
        for (int p = 0; p < 15; ++p)
            pr[p] = tq[p] * 4288 + tq[p + 1] * 64 + co;

        // ---- issue batch A: conv2 pair loads (15 x v8h = 60 VGPR) ----
        v8h A[15];
        #pragma unroll
        for (int p = 0; p < 15; ++p)
            A[p] = *reinterpret_cast<const v8h*>(g2 + pr[p]);
        SB();

        // ---- conv3 taps 0..2 from LDS, positions 0..6 (21 reads) ----
        v8h m3 = {};
        #pragma unroll
        for (int p = 0; p < 7; ++p) {
            v8h s0 = *reinterpret_cast<const v8h*>(lds +        tq[p    ] * 128 + parc);
            v8h s1 = *reinterpret_cast<const v8h*>(lds + 8576 + tq[p + 1] * 128 + parc);
            v8h s2 = *reinterpret_cast<const v8h*>(lds + 17152 + tq[p + 2] * 128 + parc);
            m3 = vmax8(m3, s0 + s1 + s2);
        }
        // ---- consume A -> m2 ----
        v8h m2 = {};
        #pragma unroll
        for (int p = 0; p < 15; ++p) m2 = vmax8(m2, A[p]);

        // ---- issue batch C: conv4 pairs p0..5 (12 x v8h = 48 VGPR) ----
        v8h C[12];
        #pragma unroll
        for (int u = 0; u < 6; ++u) {
            C[u]     = *reinterpret_cast<const v8h*>(g4a + pr[u]);
            C[6 + u] = *reinterpret_cast<const v8h*>(g4b + pr[u + 2]);
        }
        SB();

        // ---- conv3 positions 7..13 (21 reads) ----
        #pragma unroll
        for (int p = 7; p < 14; ++p) {
            v8h s0 = *reinterpret_cast<const v8h*>(lds +        tq[p    ] * 128 + parc);
            v8h s1 = *reinterpret_cast<const v8h*>(lds + 8576 + tq[p + 1] * 128 + parc);
            v8h s2 = *reinterpret_cast<const v8h*>(lds + 17152 + tq[p + 2] * 128 + parc);
            m3 = vmax8(m3, s0 + s1 + s2);
        }
        // ---- consume C -> m4 ----
        v8h m4 = {};
        #pragma unroll
        for (int u = 0; u < 6; ++u) m4 = vmax8(m4, C[u] + C[6 + u]);

        // ---- issue batch D: conv4 pairs p6..12 (14 x v8h = 56 VGPR) ----
        v8h D[14];
        #pragma unroll
        for (int u = 0; u < 7; ++u) {
            D[u]     = *reinterpret_cast<const v8h*>(g4a + pr[6 + u]);
            D[7 + u] = *reinterpret_cast<const v8h*>(g4b + pr[8 + u]);
        }
        SB();
        #pragma unroll
        for (int u = 0; u < 7; ++u) m4 = vmax8(m4, D[u] + D[7 + u]);

        // ---- projection: O[16 rows][96] via 18 MFMAs (R6-verified) ----
        #pragma unroll
        for (int u = 0; u < 6; ++u) {
            v4f acc = {0.f, 0.f, 0.f, 0.f};
            v8h w0 = *reinterpret_cast<const v8h*>(pwp + 768 * u);
            v8h w1 = *reinterpret_cast<const v8h*>(pwp + 768 * u + 16);
            v8h w2 = *reinterpret_cast<const v8h*>(pwp + 768 * u + 32);
            acc = __builtin_amdgcn_mfma_f32_16x16x32_f16(m2, w0, acc, 0, 0, 0);
            acc = __builtin_amdgcn_mfma_f32_16x16x32_f16(m3, w1, acc, 0, 0, 0);
            acc = __builtin_amdgcn_mfma_f32_16x16x32_f16(m4, w2, acc, 0, 0, 0);
            float pbl = pb[16 * u + ml];
            #pragma unroll
            for (int r = 0; r < 4; ++r)
                out[(size_t)(rowb + c * 4 + r) * NFEAT + 16 * u + ml] =
                    fmaxf(acc[r] + pbl, 0.f);
        }
    }
}

// ------------- fallback (R8 all-LDS) if ws can't hold pair tables ---------
template<int K, int N, int P0, int TB>
__device__ __forceinline__ void lconv(const char* __restrict__ base,
                                      const int (&ap)[16], v8h& m)
{
    v8h s[N];
    #pragma unroll
    for (int u = 0; u < N; ++u)
        s[u] = *reinterpret_cast<const v8h*>(base + TB + ap[P0 + u]);
    #pragma unroll
    for (int h = 1; h < K; ++h) {
        v8h t[N];
        #pragma unroll
        for (int u = 0; u < N; ++u)
            t[u] = *reinterpret_cast<const v8h*>(base + TB + h * LTS + ap[P0 + u + h]);
        #pragma unroll
        for (int u = 0; u < N; ++u) s[u] = s[u] + t[u];
    }
    #pragma unroll
    for (int u = 0; u < N; ++u) m = __builtin_elementwise_max(m, s[u]);
}

__global__ __launch_bounds__(512, 6) void fused_cnn_fb(
    const int*      __restrict__ x,
    const unsigned* __restrict__ ws,
    const float*    __restrict__ pb,
    float*          __restrict__ out)
{
    extern __shared__ __align__(16) char ldsraw[];
    const int tid = threadIdx.x;
    {
        const float4* s4 = reinterpret_cast<const float4*>(ws);
        float4* d4 = reinterpret_cast<float4*>(ldsraw);
        #pragma unroll
        for (int i0 = 0; i0 < 2560; i0 += 512) {
            int i = i0 + tid;
            if (i < 2412) {
                int t = i >> 2, cc = i & 3;
                d4[5 * t + cc] = s4[i];
            }
        }
    }
    __syncthreads();

    const int lane = tid & 63;
    const int wv   = tid >> 6;
    const int ml   = lane & 15;
    const int c    = lane >> 4;
    const int co   = c << 4;
    const int rowb = blockIdx.x * 128 + wv * 16;
    const int row  = rowb + ml;
    const char* base = ldsraw;

    const int4* xp = reinterpret_cast<const int4*>(x + row * SEQL);
    int4 q0 = xp[0], q1 = xp[1], q2 = xp[2], q3 = xp[3];
    int ap[16];
    ap[ 0] = q0.x * ESTR + co; ap[ 1] = q0.y * ESTR + co;
    ap[ 2] = q0.z * ESTR + co; ap[ 3] = q0.w * ESTR + co;
    ap[ 4] = q1.x * ESTR + co; ap[ 5] = q1.y * ESTR + co;
    ap[ 6] = q1.z * ESTR + co; ap[ 7] = q1.w * ESTR + co;
    ap[ 8] = q2.x * ESTR + co; ap[ 9] = q2.y * ESTR + co;
    ap[10] = q2.z * ESTR + co; ap[11] = q2.w * ESTR + co;
    ap[12] = q3.x * ESTR + co; ap[13] = q3.y * ESTR + co;
    ap[14] = q3.z * ESTR + co; ap[15] = q3.w * ESTR + co;

    v8h m2 = {}, m3 = {}, m4 = {};
    lconv<2, 5,  0, 0 * LTS>(base, ap, m2);
    lconv<2, 5,  5, 0 * LTS>(base, ap, m2);
    lconv<2, 5, 10, 0 * LTS>(base, ap, m2);
    lconv<3, 5,  0, 2 * LTS>(base, ap, m3);
    lconv<3, 5,  5, 2 * LTS>(base, ap, m3);
    lconv<3, 4, 10, 2 * LTS>(base, ap, m3);
    lconv<4, 5,  0, 5 * LTS>(base, ap, m4);
    lconv<4, 4,  5, 5 * LTS>(base, ap, m4);
    lconv<4, 4,  9, 5 * LTS>(base, ap, m4);

    const unsigned* __restrict__ pwp = ws + PWOFF + ml * NFP + c * 4;
    #pragma unroll
    for (int u = 0; u < 6; ++u) {
        v4f acc = {0.f, 0.f, 0.f, 0.f};
        v8h w0 = *reinterpret_cast<const v8h*>(pwp + 768 * u);
        v8h w1 = *reinterpret_cast<const v8h*>(pwp + 768 * u + 16);
        v8h w2 = *reinterpret_cast<const v8h*>(pwp + 768 * u + 32);
        acc = __builtin_amdgcn_mfma_f32_16x16x32_f16(m2, w0, acc, 0, 0, 0);
        acc = __builtin_amdgcn_mfma_f32_16x16x32_f16(m3, w1, acc, 0, 0, 0);
        acc = __builtin_amdgcn_mfma_f32_16x16x32_f16(m4, w2, acc, 0, 0, 0);
        float pbl = pb[16 * u + ml];
        #pragma unroll
        for (int r = 0; r < 4; ++r)
            out[(size_t)(rowb + c * 4 + r) * NFEAT + 16 * u + ml] =
                fmaxf(acc[r] + pbl, 0.f);
    }
}

extern "C" void kernel_launch(void* const* d_in, const int* in_sizes, int n_in,
                              void* d_out, int out_size, void* d_ws, size_t ws_size,
                              hipStream_t stream)
{
    const int*   x     = (const int*)  d_in[0];
    const float* embed = (const float*)d_in[1];
    const float* w2    = (const float*)d_in[2];
    const float* b2    = (const float*)d_in[3];
    const float* w3    = (const float*)d_in[4];
    const float* b3    = (const float*)d_in[5];
    const float* w4    = (const float*)d_in[6];
    const float* b4    = (const float*)d_in[7];
    const float* pw    = (const float*)d_in[8];
    const float* pb    = (const float*)d_in[9];
    float* out = (float*)d_out;
    unsigned* ws = (unsigned*)d_ws;

    build_tables<<<(PAIRW + 255) / 256, 256, 0, stream>>>(
        embed, w2, b2, w3, b3, w4, b4, pw, ws);

    if (ws_size >= (size_t)WSNEED) {
        build_pairs3<<<(3 * PRW + 255) / 256, 256, 0, stream>>>(ws);
        // persistent: 512 blocks = exactly 2/CU resident; 2 chunks each.
        fused_cnn<<<512, 512, 0, stream>>>(x, ws, pb, out);
    } else {
        (void)hipFuncSetAttribute((const void*)fused_cnn_fb,
                                  hipFuncAttributeMaxDynamicSharedMemorySize,
                                  LDSB8);
        fused_cnn_fb<<<BATCH / 128, 512, LDSB8, stream>>>(x, ws, pb, out);
    }
}

// Round 15
// 49.454 us; speedup vs baseline: 1.9955x; 1.9955x over previous
//
#include <hip/hip_runtime.h>
#include <hip/hip_fp16.h>

// GeneSymbolCNN: embed(67x32, pad0) -> conv1d k=2/3/4 (32ch) + ReLU + max_t
//                -> concat(96) -> 96x96 linear + ReLU.
// R15 = R8 (best: 41.0us total) + atomic WORK-STEALING to remove the
// scheduling tail. R8's 1024 blocks at 3-resident/CU ran a 768-block
// saturated phase then a 256-block 1/CU phase (~half efficiency, +8-12us).
// Here grid = 768 = exactly 3 blocks/CU, each stages LDS ONCE and pulls
// 128-row chunks (0..1023) from an atomic counter in ws (zeroed by
// build_tables each launch -> deterministic; chunk->rows fixed so output
// is identical regardless of claim order; graph-capture safe).
// Compute body is VERBATIM R8: 80B-padded f16 tap tables in LDS (48.2KB,
// unreplicated; span=(5t+c)&7 scatter), channel-split 4 thr/row, conv
// output = mfma_f32_16x16x32_f16 A-fragment, 18-MFMA projection.
// R7/R9/R10/R14 lesson (final): hipcc either serializes (VGPR 36-40) or
// scratch-spills (R14: FETCH 120MB) large scattered-gather batches --
// never again; LDS-lookup + compiler scheduling is the reliable shape.

#define VOCABSZ 67
#define EMBSZ   32
#define NCH     32
#define NFEAT   96
#define SEQL    16
#define BATCH   131072
#define NTAB    9
#define NFP     (NFEAT / 2)
#define TABU    9648                   // 603 entries * 16 u32 (f16 tap tables)
#define PWOFF   9648                   // packed pw follows
#define NPW     4608                   // 14256 words total
#define CNTW    14336                  // atomic chunk counter (u32 word idx)
#define NCHUNK  1024                   // 1024 chunks * 128 rows = BATCH
#define ESTR    80                     // LDS bytes per entry (64 + 16 pad)
#define LTS     (VOCABSZ * ESTR)       // 5360 B per table
#define LDSB    (NTAB * LTS + 16)     // 48240 tables + chunk-broadcast slot

typedef _Float16 v2h __attribute__((ext_vector_type(2)));
typedef _Float16 v8h __attribute__((ext_vector_type(8)));
typedef float    v4f __attribute__((ext_vector_type(4)));

__device__ __forceinline__ unsigned packh2(float a, float b) {
    v2h p; p[0] = (_Float16)a; p[1] = (_Float16)b;
    return __builtin_bit_cast(unsigned, p);
}

// ------------- kernel 1: f16 tap tables + packed pw + counter reset -------
__global__ __launch_bounds__(256) void build_tables(
    const float* __restrict__ embed,
    const float* __restrict__ w2, const float* __restrict__ b2,
    const float* __restrict__ w3, const float* __restrict__ b3,
    const float* __restrict__ w4, const float* __restrict__ b4,
    const float* __restrict__ pw,
    unsigned* __restrict__ ws)
{
    int idx = blockIdx.x * 256 + threadIdx.x;
    if (idx == CNTW) ws[idx] = 0u;         // reset work-stealing counter
    if (idx < TABU) {                      // one half2 (2 channels) per thread
        int cp = idx & 15;                 // channel pair 0..15
        int t  = idx >> 4;                 // j*67 + v
        int j  = t / VOCABSZ;
        int v  = t - j * VOCABSZ;
        const float* w; const float* bias; int k, h;
        if (j < 2)      { w = w2; k = 2; h = j;     bias = (h == 0) ? b2 : nullptr; }
        else if (j < 5) { w = w3; k = 3; h = j - 2; bias = (h == 0) ? b3 : nullptr; }
        else            { w = w4; k = 4; h = j - 5; bias = (h == 0) ? b4 : nullptr; }
        int c0 = 2 * cp;
        float a0 = bias ? bias[c0]     : 0.0f;
        float a1 = bias ? bias[c0 + 1] : 0.0f;
        if (v != 0) {                      // padding_idx=0: row 0 is zeros
            #pragma unroll
            for (int e = 0; e < EMBSZ; ++e) {
                float ev = embed[v * EMBSZ + e];
                a0 += ev * w[((c0    ) * EMBSZ + e) * k + h];
                a1 += ev * w[((c0 + 1) * EMBSZ + e) * k + h];
            }
        }
        ws[t * 16 + cp] = packh2(a0, a1);
    } else if (idx < TABU + NPW) {         // packed pw: pwh[o][fp]
        int i  = idx - PWOFF;
        int o  = i / NFP;
        int fp = i - o * NFP;
        ws[PWOFF + i] = packh2(pw[o * NFEAT + 2 * fp], pw[o * NFEAT + 2 * fp + 1]);
    }
}

// ------------- R8 conv batch: N positions, K taps, table base TB ----------
// All indices compile-time after unroll (rule #20).
template<int K, int N, int P0, int TB>
__device__ __forceinline__ void lconv(const char* __restrict__ base,
                                      const int (&ap)[16], v8h& m)
{
    v8h s[N];
    #pragma unroll
    for (int u = 0; u < N; ++u)
        s[u] = *reinterpret_cast<const v8h*>(base + TB + ap[P0 + u]);
    #pragma unroll
    for (int h = 1; h < K; ++h) {
        v8h t[N];
        #pragma unroll
        for (int u = 0; u < N; ++u)
            t[u] = *reinterpret_cast<const v8h*>(base + TB + h * LTS + ap[P0 + u + h]);
        #pragma unroll
        for (int u = 0; u < N; ++u) s[u] = s[u] + t[u];
    }
    #pragma unroll
    for (int u = 0; u < N; ++u) m = __builtin_elementwise_max(m, s[u]);
}

// ------------- kernel 2: work-stealing fused conv + MFMA projection -------
__global__ __launch_bounds__(512, 6) void fused_cnn(
    const int*      __restrict__ x,
    unsigned*       __restrict__ ws,
    const float*    __restrict__ pb,
    float*          __restrict__ out)
{
    extern __shared__ __align__(16) char ldsraw[];
    const int tid = threadIdx.x;
    {   // stage 2412 float4 of tables into 80B-strided entries, ONCE
        const float4* s4 = reinterpret_cast<const float4*>(ws);
        float4* d4 = reinterpret_cast<float4*>(ldsraw);
        #pragma unroll
        for (int i0 = 0; i0 < 2560; i0 += 512) {
            int i = i0 + tid;
            if (i < 2412) {
                int t = i >> 2, cc = i & 3;
                d4[5 * t + cc] = s4[i];
            }
        }
    }
    volatile int* slot = reinterpret_cast<volatile int*>(ldsraw + NTAB * LTS);
    unsigned* cnt = ws + CNTW;

    const int lane = tid & 63;
    const int wv   = tid >> 6;
    const int ml   = lane & 15;
    const int c    = lane >> 4;
    const int co   = c << 4;
    const char* base = ldsraw;
    const unsigned* __restrict__ pwp = ws + PWOFF + ml * NFP + c * 4;

    for (;;) {
        if (tid == 0) *slot = (int)atomicAdd(cnt, 1u);
        __syncthreads();                   // slot written before reads
        const int chunk = *slot;
        __syncthreads();                   // all reads done before next write
        if (chunk >= NCHUNK) break;        // uniform exit

        const int rowb = chunk * 128 + wv * 16;
        const int row  = rowb + ml;

        const int4* xp = reinterpret_cast<const int4*>(x + row * SEQL);
        int4 q0 = xp[0], q1 = xp[1], q2 = xp[2], q3 = xp[3];
        int ap[16];
        ap[ 0] = q0.x * ESTR + co; ap[ 1] = q0.y * ESTR + co;
        ap[ 2] = q0.z * ESTR + co; ap[ 3] = q0.w * ESTR + co;
        ap[ 4] = q1.x * ESTR + co; ap[ 5] = q1.y * ESTR + co;
        ap[ 6] = q1.z * ESTR + co; ap[ 7] = q1.w * ESTR + co;
        ap[ 8] = q2.x * ESTR + co; ap[ 9] = q2.y * ESTR + co;
        ap[10] = q2.z * ESTR + co; ap[11] = q2.w * ESTR + co;
        ap[12] = q3.x * ESTR + co; ap[13] = q3.y * ESTR + co;
        ap[14] = q3.z * ESTR + co; ap[15] = q3.w * ESTR + co;

        v8h m2 = {}, m3 = {}, m4 = {};     // feats >= 0 -> 0-init max-safe
        lconv<2, 5,  0, 0 * LTS>(base, ap, m2);
        lconv<2, 5,  5, 0 * LTS>(base, ap, m2);
        lconv<2, 5, 10, 0 * LTS>(base, ap, m2);
        lconv<3, 5,  0, 2 * LTS>(base, ap, m3);
        lconv<3, 5,  5, 2 * LTS>(base, ap, m3);
        lconv<3, 4, 10, 2 * LTS>(base, ap, m3);
        lconv<4, 5,  0, 5 * LTS>(base, ap, m4);
        lconv<4, 4,  5, 5 * LTS>(base, ap, m4);
        lconv<4, 4,  9, 5 * LTS>(base, ap, m4);

        // ---- projection: O[16 rows][96] via 18 MFMAs (R6-verified) ----
        #pragma unroll
        for (int u = 0; u < 6; ++u) {
            v4f acc = {0.f, 0.f, 0.f, 0.f};
            v8h w0 = *reinterpret_cast<const v8h*>(pwp + 768 * u);
            v8h w1 = *reinterpret_cast<const v8h*>(pwp + 768 * u + 16);
            v8h w2 = *reinterpret_cast<const v8h*>(pwp + 768 * u + 32);
            acc = __builtin_amdgcn_mfma_f32_16x16x32_f16(m2, w0, acc, 0, 0, 0);
            acc = __builtin_amdgcn_mfma_f32_16x16x32_f16(m3, w1, acc, 0, 0, 0);
            acc = __builtin_amdgcn_mfma_f32_16x16x32_f16(m4, w2, acc, 0, 0, 0);
            float pbl = pb[16 * u + ml];
            #pragma unroll
            for (int r = 0; r < 4; ++r)
                out[(size_t)(rowb + c * 4 + r) * NFEAT + 16 * u + ml] =
                    fmaxf(acc[r] + pbl, 0.f);
        }
    }
}

extern "C" void kernel_launch(void* const* d_in, const int* in_sizes, int n_in,
                              void* d_out, int out_size, void* d_ws, size_t ws_size,
                              hipStream_t stream)
{
    const int*   x     = (const int*)  d_in[0];
    const float* embed = (const float*)d_in[1];
    const float* w2    = (const float*)d_in[2];
    const float* b2    = (const float*)d_in[3];
    const float* w3    = (const float*)d_in[4];
    const float* b3    = (const float*)d_in[5];
    const float* w4    = (const float*)d_in[6];
    const float* b4    = (const float*)d_in[7];
    const float* pw    = (const float*)d_in[8];
    const float* pb    = (const float*)d_in[9];
    float* out = (float*)d_out;
    unsigned* ws = (unsigned*)d_ws;        // tables+pw 57KB, counter at 57.3KB

    build_tables<<<(CNTW + 256) / 256, 256, 0, stream>>>(
        embed, w2, b2, w3, b3, w4, b4, pw, ws);

    (void)hipFuncSetAttribute((const void*)fused_cnn,
                              hipFuncAttributeMaxDynamicSharedMemorySize,
                              LDSB);
    // 768 blocks = exactly 3/CU resident (48.2KB LDS); each steals 128-row
    // chunks until the 1024 chunks are gone -> no scheduling tail.
    fused_cnn<<<768, 512, LDSB, stream>>>(x, ws, pb, out);
}

// Round 16
// 48.417 us; speedup vs baseline: 2.0382x; 1.0214x over previous
//
#include <hip/hip_runtime.h>
#include <hip/hip_fp16.h>

// GeneSymbolCNN: embed(67x32, pad0) -> conv1d k=2/3/4 (32ch) + ReLU + max_t
//                -> concat(96) -> 96x96 linear + ReLU.
// R16 = R8 body with UNPADDED 64B entries + fully-resident grid.
//  Evidence chain:
//   * R3 (64B stride) conflict tax 6.3 cyc/instr vs R8 (80B pad) 5.7 --
//     the pad buys ~10% on the LDS pipe but costs 25% LDS capacity.
//   * Unpadded: 9 tables x 67 x 64B = 38.6KB -> 4 blocks/CU -> ALL 1024
//     blocks resident at once (256 CU x 4). No scheduling generations, no
//     tail (R8 lost ~10us there), no work-stealing loop (R15: spilled).
//   * 32 waves/CU (8/SIMD, max TLP) needs VGPR <= 64: R8's straight-line
//     body compiles to ~48 naturally; __launch_bounds__(512,8) caps at 64.
//  Body is verbatim R8: channel-split 4 thr/row (c = lane>>4 owns 16B
//  chunk), conv output v8h = mfma_f32_16x16x32_f16 A-fragment directly,
//  18-MFMA projection (R6-verified layouts), pw packed wave-uniform.
//  R7/R9/R10/R14/R15 lesson: no scattered global gathers, no liveness
//  tricks, no loops around the body -- compiler-scheduled LDS lookups only.

#define VOCABSZ 67
#define EMBSZ   32
#define NCH     32
#define NFEAT   96
#define SEQL    16
#define BATCH   131072
#define NTAB    9
#define NFP     (NFEAT / 2)
#define TABU    9648                   // 603 entries * 16 u32 (f16 tap tables)
#define PWOFF   9648                   // packed pw follows
#define NPW     4608
#define ESTR    64                     // LDS bytes per entry (UNPADDED)
#define LTS     (VOCABSZ * ESTR)       // 4288 B per table
#define LDSB    (NTAB * LTS)           // 38592 B -> 4 blocks/CU

typedef _Float16 v2h __attribute__((ext_vector_type(2)));
typedef _Float16 v8h __attribute__((ext_vector_type(8)));
typedef float    v4f __attribute__((ext_vector_type(4)));

__device__ __forceinline__ unsigned packh2(float a, float b) {
    v2h p; p[0] = (_Float16)a; p[1] = (_Float16)b;
    return __builtin_bit_cast(unsigned, p);
}

// ------------- kernel 1: f16 tap tables + packed pw -----------------------
__global__ __launch_bounds__(256) void build_tables(
    const float* __restrict__ embed,
    const float* __restrict__ w2, const float* __restrict__ b2,
    const float* __restrict__ w3, const float* __restrict__ b3,
    const float* __restrict__ w4, const float* __restrict__ b4,
    const float* __restrict__ pw,
    unsigned* __restrict__ ws)
{
    int idx = blockIdx.x * 256 + threadIdx.x;
    if (idx < TABU) {                      // one half2 (2 channels) per thread
        int cp = idx & 15;                 // channel pair 0..15
        int t  = idx >> 4;                 // j*67 + v
        int j  = t / VOCABSZ;
        int v  = t - j * VOCABSZ;
        const float* w; const float* bias; int k, h;
        if (j < 2)      { w = w2; k = 2; h = j;     bias = (h == 0) ? b2 : nullptr; }
        else if (j < 5) { w = w3; k = 3; h = j - 2; bias = (h == 0) ? b3 : nullptr; }
        else            { w = w4; k = 4; h = j - 5; bias = (h == 0) ? b4 : nullptr; }
        int c0 = 2 * cp;
        float a0 = bias ? bias[c0]     : 0.0f;
        float a1 = bias ? bias[c0 + 1] : 0.0f;
        if (v != 0) {                      // padding_idx=0: row 0 is zeros
            #pragma unroll
            for (int e = 0; e < EMBSZ; ++e) {
                float ev = embed[v * EMBSZ + e];
                a0 += ev * w[((c0    ) * EMBSZ + e) * k + h];
                a1 += ev * w[((c0 + 1) * EMBSZ + e) * k + h];
            }
        }
        ws[t * 16 + cp] = packh2(a0, a1);
    } else if (idx < TABU + NPW) {         // packed pw: pwh[o][fp]
        int i  = idx - PWOFF;
        int o  = i / NFP;
        int fp = i - o * NFP;
        ws[PWOFF + i] = packh2(pw[o * NFEAT + 2 * fp], pw[o * NFEAT + 2 * fp + 1]);
    }
}

// ------------- conv batch: N positions, K taps, table base byte TB --------
// All indices compile-time after unroll (rule #20). N loads in flight/tap.
template<int K, int N, int P0, int TB>
__device__ __forceinline__ void lconv(const char* __restrict__ base,
                                      const int (&ap)[16], v8h& m)
{
    v8h s[N];
    #pragma unroll
    for (int u = 0; u < N; ++u)
        s[u] = *reinterpret_cast<const v8h*>(base + TB + ap[P0 + u]);
    #pragma unroll
    for (int h = 1; h < K; ++h) {
        v8h t[N];
        #pragma unroll
        for (int u = 0; u < N; ++u)
            t[u] = *reinterpret_cast<const v8h*>(base + TB + h * LTS + ap[P0 + u + h]);
        #pragma unroll
        for (int u = 0; u < N; ++u) s[u] = s[u] + t[u];
    }
    #pragma unroll
    for (int u = 0; u < N; ++u) m = __builtin_elementwise_max(m, s[u]);
}

// ------------- kernel 2: fused conv-as-lookup + max + MFMA projection -----
__global__ __launch_bounds__(512, 8) void fused_cnn(
    const int*      __restrict__ x,
    const unsigned* __restrict__ ws,
    const float*    __restrict__ pb,
    float*          __restrict__ out)
{
    extern __shared__ __align__(16) char ldsraw[];
    const int tid = threadIdx.x;
    {   // stage 2412 float4 of tables, linear (unpadded 64B entries)
        const float4* s4 = reinterpret_cast<const float4*>(ws);
        float4* d4 = reinterpret_cast<float4*>(ldsraw);
        #pragma unroll
        for (int i0 = 0; i0 < 2560; i0 += 512) {
            int i = i0 + tid;
            if (i < 2412) d4[i] = s4[i];
        }
    }
    __syncthreads();

    const int lane = tid & 63;
    const int wv   = tid >> 6;               // wave 0..7
    const int ml   = lane & 15;              // batch row in wave's 16-row tile
    const int c    = lane >> 4;              // chunk = MFMA k-group
    const int co   = c << 4;                 // chunk byte offset in entry
    const int rowb = blockIdx.x * 128 + wv * 16;
    const int row  = rowb + ml;
    const char* base = ldsraw;

    const int4* xp = reinterpret_cast<const int4*>(x + row * SEQL);
    int4 q0 = xp[0], q1 = xp[1], q2 = xp[2], q3 = xp[3];
    int ap[16];                               // entry byte offset + chunk
    ap[ 0] = (q0.x << 6) + co; ap[ 1] = (q0.y << 6) + co;
    ap[ 2] = (q0.z << 6) + co; ap[ 3] = (q0.w << 6) + co;
    ap[ 4] = (q1.x << 6) + co; ap[ 5] = (q1.y << 6) + co;
    ap[ 6] = (q1.z << 6) + co; ap[ 7] = (q1.w << 6) + co;
    ap[ 8] = (q2.x << 6) + co; ap[ 9] = (q2.y << 6) + co;
    ap[10] = (q2.z << 6) + co; ap[11] = (q2.w << 6) + co;
    ap[12] = (q3.x << 6) + co; ap[13] = (q3.y << 6) + co;
    ap[14] = (q3.z << 6) + co; ap[15] = (q3.w << 6) + co;

    v8h m2 = {}, m3 = {}, m4 = {};            // feats >= 0 -> 0-init max-safe

    // conv2: tables 0,1 ; positions 0..14
    lconv<2, 5,  0, 0 * LTS>(base, ap, m2);
    lconv<2, 5,  5, 0 * LTS>(base, ap, m2);
    lconv<2, 5, 10, 0 * LTS>(base, ap, m2);
    // conv3: tables 2,3,4 ; positions 0..13
    lconv<3, 5,  0, 2 * LTS>(base, ap, m3);
    lconv<3, 5,  5, 2 * LTS>(base, ap, m3);
    lconv<3, 4, 10, 2 * LTS>(base, ap, m3);
    // conv4: tables 5,6,7,8 ; positions 0..12
    lconv<4, 5,  0, 5 * LTS>(base, ap, m4);
    lconv<4, 4,  5, 5 * LTS>(base, ap, m4);
    lconv<4, 4,  9, 5 * LTS>(base, ap, m4);

    // ---- projection: O[16 rows][96] = feat x pw^T via 18 mfma 16x16x32 ----
    // A-fragment: lane holds A[ml][8c..8c+7] per k-tile = m2/m3/m4 directly.
    const unsigned* __restrict__ pwp = ws + PWOFF + ml * NFP + c * 4;
    #pragma unroll
    for (int u = 0; u < 6; ++u) {
        v4f acc = {0.f, 0.f, 0.f, 0.f};
        v8h w0 = *reinterpret_cast<const v8h*>(pwp + 768 * u);
        v8h w1 = *reinterpret_cast<const v8h*>(pwp + 768 * u + 16);
        v8h w2 = *reinterpret_cast<const v8h*>(pwp + 768 * u + 32);
        acc = __builtin_amdgcn_mfma_f32_16x16x32_f16(m2, w0, acc, 0, 0, 0);
        acc = __builtin_amdgcn_mfma_f32_16x16x32_f16(m3, w1, acc, 0, 0, 0);
        acc = __builtin_amdgcn_mfma_f32_16x16x32_f16(m4, w2, acc, 0, 0, 0);
        // D: row m = c*4 + r (local), col n = 16u + ml. Bias + ReLU at store.
        float pbl = pb[16 * u + ml];
        #pragma unroll
        for (int r = 0; r < 4; ++r)
            out[(size_t)(rowb + c * 4 + r) * NFEAT + 16 * u + ml] =
                fmaxf(acc[r] + pbl, 0.f);
    }
}

extern "C" void kernel_launch(void* const* d_in, const int* in_sizes, int n_in,
                              void* d_out, int out_size, void* d_ws, size_t ws_size,
                              hipStream_t stream)
{
    const int*   x     = (const int*)  d_in[0];
    const float* embed = (const float*)d_in[1];
    const float* w2    = (const float*)d_in[2];
    const float* b2    = (const float*)d_in[3];
    const float* w3    = (const float*)d_in[4];
    const float* b3    = (const float*)d_in[5];
    const float* w4    = (const float*)d_in[6];
    const float* b4    = (const float*)d_in[7];
    const float* pw    = (const float*)d_in[8];
    const float* pb    = (const float*)d_in[9];
    float* out = (float*)d_out;
    unsigned* ws = (unsigned*)d_ws;      // 9648 + 4608 u32 = 57 KB used

    build_tables<<<(TABU + NPW + 255) / 256, 256, 0, stream>>>(
        embed, w2, b2, w3, b3, w4, b4, pw, ws);

    // 4 threads/row, 128 rows/block -> grid 1024 = 256 CU x 4 blocks
    // (38.6KB LDS each): the ENTIRE grid is resident -> no tail.
    // 32 waves/CU at VGPR <= 64 (launch_bounds 512,8).
    fused_cnn<<<BATCH / 128, 512, LDSB, stream>>>(x, ws, pb, out);
}